// Round 1
// baseline (1528.972 us; speedup 1.0000x reference)
//
#include <hip/hip_runtime.h>

#define N_BOX 1805
#define NPIX 361

__device__ __forceinline__ float leakyf(float x){ return x > 0.f ? x : 0.1f*x; }
__device__ __forceinline__ float sigmoidf_(float x){ return 1.f/(1.f + expf(-x)); }

// ---------------- small transpose: dst[C][R] = src[R][C] ----------------
__global__ void transpose_k(const float* __restrict__ src, float* __restrict__ dst, int R, int C){
  int i = blockIdx.x*256 + threadIdx.x;
  if (i < R*C){ int r = i / C, c = i % C; dst[c*R + r] = src[i]; }
}

// ---------------- reorg path: leaky(conv1x1(feat2, wr)+br) -> reorg -> cat[0:256] ----------------
// block 256 = 64 channels x 4 pixels; grid 361 (1444 pixels of 38x38)
__global__ __launch_bounds__(256) void reorg_conv_k(const float* __restrict__ feat2,
    const float* __restrict__ wrT, const float* __restrict__ br, float* __restrict__ cat){
  int c  = threadIdx.x & 63;
  int pq = threadIdx.x >> 6;
  int pix = blockIdx.x*4 + pq;      // 0..1443
  int y = pix / 38, x = pix % 38;
  __shared__ float s_in[64][4];
  float acc = br[c];
  for (int cb = 0; cb < 512; cb += 64){
    __syncthreads();
    { int k = threadIdx.x >> 2, pp = threadIdx.x & 3;
      s_in[k][pp] = feat2[(cb + k)*1444 + blockIdx.x*4 + pp]; }
    __syncthreads();
    #pragma unroll
    for (int k = 0; k < 64; ++k)
      acc = fmaf(wrT[(cb+k)*64 + c], s_in[k][pq], acc);
  }
  float v = leakyf(acc);
  int co = ((y & 1)*2 + (x & 1))*64 + c;   // reorg channel mapping
  cat[co*NPIX + (y>>1)*19 + (x>>1)] = v;
}

// ---------------- generic 3x3 conv on 19x19, split-K partials ----------------
#define CO_TILE 16
#define CTHREADS 384
#define CI_CHUNK 8

__global__ __launch_bounds__(CTHREADS) void conv3x3_part_k(const float* __restrict__ in,
    const float* __restrict__ w, float* __restrict__ part, int Cin, int kchunk){
  const int Cout = 1024;
  int kc  = blockIdx.y;             // split-K index (8)
  int cob = blockIdx.x * CO_TILE;   // out-channel base
  int ci0 = kc * kchunk;
  __shared__ float tile[CI_CHUNK][441];   // padded 21x21 per channel
  int tid = threadIdx.x;
  int p = tid, py = p / 19, px = p % 19;
  float acc[CO_TILE];
  #pragma unroll
  for (int i = 0; i < CO_TILE; ++i) acc[i] = 0.f;

  for (int cc = 0; cc < kchunk; cc += CI_CHUNK){
    __syncthreads();
    for (int idx = tid; idx < CI_CHUNK*441; idx += CTHREADS){
      int c = idx / 441, r = idx % 441;
      int yy = r / 21 - 1, xx = r % 21 - 1;
      float v = 0.f;
      if ((unsigned)yy < 19u && (unsigned)xx < 19u)
        v = in[(ci0 + cc + c)*NPIX + yy*19 + xx];
      tile[c][r] = v;
    }
    __syncthreads();
    if (p < NPIX){
      #pragma unroll
      for (int c = 0; c < CI_CHUNK; ++c){
        float iv[9];
        #pragma unroll
        for (int dy = 0; dy < 3; ++dy)
          #pragma unroll
          for (int dx = 0; dx < 3; ++dx)
            iv[dy*3+dx] = tile[c][(py+dy)*21 + (px+dx)];
        const float* wb = w + ((size_t)cob * Cin + (ci0 + cc + c)) * 9;
        #pragma unroll
        for (int co = 0; co < CO_TILE; ++co){
          const float* wp = wb + (size_t)co * Cin * 9;   // uniform -> s_load
          #pragma unroll
          for (int t = 0; t < 9; ++t) acc[co] = fmaf(wp[t], iv[t], acc[co]);
        }
      }
    }
  }
  if (p < NPIX){
    #pragma unroll
    for (int co = 0; co < CO_TILE; ++co)
      part[(size_t)kc*Cout*NPIX + (cob+co)*NPIX + p] = acc[co];
  }
}

// ---------------- reduce split-K partials + bias + leaky ----------------
__global__ void reduce_k(const float* __restrict__ part, const float* __restrict__ bias,
                         float* __restrict__ out, int total, int do_leaky){
  int i = blockIdx.x*256 + threadIdx.x;
  if (i >= total) return;
  int co = i / NPIX;
  float s = bias[co];
  #pragma unroll
  for (int k = 0; k < 8; ++k) s += part[(size_t)k*total + i];
  out[i] = do_leaky ? leakyf(s) : s;
}

// ---------------- pred 1x1 conv: 1024 -> 125 ----------------
// block 256 = 128 ch-slots x 2 pixels (125 active); grid 181
__global__ __launch_bounds__(256) void pred_conv_k(const float* __restrict__ t3,
    const float* __restrict__ wpT, const float* __restrict__ bp, float* __restrict__ pred){
  int c = threadIdx.x & 127, ph = threadIdx.x >> 7;
  int pix = blockIdx.x*2 + ph;
  __shared__ float s_in[64][2];
  float acc = 0.f;
  for (int cb = 0; cb < 1024; cb += 64){
    __syncthreads();
    if (threadIdx.x < 128){
      int k = threadIdx.x & 63, pp = threadIdx.x >> 6;
      int px2 = blockIdx.x*2 + pp;
      s_in[k][pp] = (px2 < NPIX) ? t3[(cb+k)*NPIX + px2] : 0.f;
    }
    __syncthreads();
    if (c < 125){
      #pragma unroll
      for (int k = 0; k < 64; ++k)
        acc = fmaf(wpT[(cb+k)*125 + c], s_in[k][ph], acc);
    }
  }
  if (c < 125 && pix < NPIX) pred[c*NPIX + pix] = acc + bp[c];
}

// ---------------- decode boxes / scores / argmax ----------------
__device__ const float ANCW[5] = {1.19f, 2.79f, 4.53f, 8.06f, 10.32f};
__device__ const float ANCH_[5] = {1.98f, 4.59f, 8.92f, 5.29f, 10.65f};

__global__ void decode_k(const float* __restrict__ pred, float* __restrict__ out,
                         int* __restrict__ cls_i){
  int n = blockIdx.x*256 + threadIdx.x;
  if (n >= N_BOX) return;
  int p = n / 5, a = n % 5;
  float conf = pred[a*NPIX + p];
  float cl[20]; float m = -1e30f;
  #pragma unroll
  for (int k = 0; k < 20; ++k){ cl[k] = pred[(5 + a*20 + k)*NPIX + p]; m = fmaxf(m, cl[k]); }
  float s = 0.f;
  #pragma unroll
  for (int k = 0; k < 20; ++k){ cl[k] = expf(cl[k]-m); s += cl[k]; }
  int bi = 0; float bv = cl[0];
  #pragma unroll
  for (int k = 1; k < 20; ++k) if (cl[k] > bv){ bv = cl[k]; bi = k; }
  float score = sigmoidf_(conf) * (bv / s);
  float tx = pred[(105 + a*4 + 0)*NPIX + p];
  float ty = pred[(105 + a*4 + 1)*NPIX + p];
  float tw = pred[(105 + a*4 + 2)*NPIX + p];
  float th = pred[(105 + a*4 + 3)*NPIX + p];
  float gx = (float)(p % 19), gy = (float)(p / 19);
  float cx = (sigmoidf_(tx) + gx) * 32.f;
  float cy = (sigmoidf_(ty) + gy) * 32.f;
  float bw = expf(tw) * ANCW[a] * 32.f;
  float bh = expf(th) * ANCH_[a] * 32.f;
  float x1 = fminf(fmaxf((cx - 0.5f*bw) / 608.f, 0.f), 1.f);
  float y1 = fminf(fmaxf((cy - 0.5f*bh) / 608.f, 0.f), 1.f);
  float x2 = fminf(fmaxf((cx + 0.5f*bw) / 608.f, 0.f), 1.f);
  float y2 = fminf(fmaxf((cy + 0.5f*bh) / 608.f, 0.f), 1.f);
  out[n*4+0]=x1; out[n*4+1]=y1; out[n*4+2]=x2; out[n*4+3]=y2;
  out[7220 + n]  = score;
  out[9025 + n]  = (float)bi;
  out[10830 + n] = 0.f;          // keep init
  cls_i[n] = bi;
}

// ---------------- per-class NMS (block per class) ----------------
__global__ __launch_bounds__(256) void nms_k(const float* __restrict__ boxes,
    const float* __restrict__ scores, const int* __restrict__ cls_i, float* __restrict__ keep){
  __shared__ float s_sc[N_BOX];
  __shared__ unsigned short s_ord[N_BOX];
  __shared__ unsigned char s_sup[N_BOX];
  __shared__ int s_n;
  int c = blockIdx.x, tid = threadIdx.x;
  if (tid == 0) s_n = 0;
  for (int i = tid; i < N_BOX; i += 256){
    s_sc[i] = (cls_i[i] == c) ? scores[i] : -1.f;   // scores are strictly > 0
    s_sup[i] = 0;
  }
  __syncthreads();
  int cnt = 0;
  for (int i = tid; i < N_BOX; i += 256){
    float si = s_sc[i];
    if (si > -0.5f){
      int r = 0;
      for (int j = 0; j < N_BOX; ++j){
        float sj = s_sc[j];
        r += (sj > si) || (sj == si && j < i);   // stable sort by (-score, index)
      }
      s_ord[r] = (unsigned short)i;
      cnt++;
    }
  }
  atomicAdd(&s_n, cnt);
  __syncthreads();
  int n = s_n;
  for (int k = 0; k < n; ++k){
    if (!s_sup[k]){                         // block-uniform
      int bk = s_ord[k];
      if (tid == 0) keep[bk] = 1.f;
      float ax1 = boxes[bk*4+0], ay1 = boxes[bk*4+1], ax2 = boxes[bk*4+2], ay2 = boxes[bk*4+3];
      float areaA = (ax2-ax1)*(ay2-ay1);
      for (int j = k+1+tid; j < n; j += 256){
        int bj = s_ord[j];
        float bx1 = boxes[bj*4+0], by1 = boxes[bj*4+1], bx2 = boxes[bj*4+2], by2 = boxes[bj*4+3];
        float iw = fmaxf(1e-10f, fminf(ax2,bx2) - fmaxf(ax1,bx1));
        float ih = fmaxf(1e-10f, fminf(ay2,by2) - fmaxf(ay1,by1));
        float inter = iw*ih;
        float areaB = (bx2-bx1)*(by2-by1);
        float iou = inter / (areaA + areaB - inter);
        if (iou > 0.5f) s_sup[j] = 1;
      }
    }
    __syncthreads();
  }
}

extern "C" void kernel_launch(void* const* d_in, const int* in_sizes, int n_in,
                              void* d_out, int out_size, void* d_ws, size_t ws_size,
                              hipStream_t stream){
  const float* feat2 = (const float*)d_in[0];   // (512,38,38)
  const float* feat3 = (const float*)d_in[1];   // (1024,19,19)
  const float* w1a = (const float*)d_in[2];
  const float* b1a = (const float*)d_in[3];
  const float* w1b = (const float*)d_in[4];
  const float* b1b = (const float*)d_in[5];
  const float* wr  = (const float*)d_in[6];
  const float* br  = (const float*)d_in[7];
  const float* w2  = (const float*)d_in[8];
  const float* b2  = (const float*)d_in[9];
  const float* wp  = (const float*)d_in[10];
  const float* bp  = (const float*)d_in[11];
  float* out = (float*)d_out;
  float* ws  = (float*)d_ws;

  float* cat  = ws;                    // 1280*361
  float* t1   = cat + 1280*NPIX;       // 1024*361 (reused for conv3 output)
  float* part = t1 + 1024*NPIX;        // 8*1024*361
  float* pred = part + 8*1024*NPIX;    // 125*361
  float* wrT  = pred + 125*NPIX;       // 512*64
  float* wpT  = wrT + 512*64;          // 1024*125
  int*   cls_i = (int*)(wpT + 1024*125);

  transpose_k<<<(64*512 + 255)/256, 256, 0, stream>>>(wr, wrT, 64, 512);
  transpose_k<<<(125*1024 + 255)/256, 256, 0, stream>>>(wp, wpT, 125, 1024);
  reorg_conv_k<<<361, 256, 0, stream>>>(feat2, wrT, br, cat);

  dim3 cg(64, 8);
  // conv1: feat3 (1024) -> t1
  conv3x3_part_k<<<cg, CTHREADS, 0, stream>>>(feat3, w1a, part, 1024, 128);
  reduce_k<<<(1024*NPIX + 255)/256, 256, 0, stream>>>(part, b1a, t1, 1024*NPIX, 1);
  // conv2: t1 (1024) -> cat[256:1280]
  conv3x3_part_k<<<cg, CTHREADS, 0, stream>>>(t1, w1b, part, 1024, 128);
  reduce_k<<<(1024*NPIX + 255)/256, 256, 0, stream>>>(part, b1b, cat + 256*NPIX, 1024*NPIX, 1);
  // conv3: cat (1280) -> t1
  conv3x3_part_k<<<cg, CTHREADS, 0, stream>>>(cat, w2, part, 1280, 160);
  reduce_k<<<(1024*NPIX + 255)/256, 256, 0, stream>>>(part, b2, t1, 1024*NPIX, 1);
  // pred 1x1: t1 -> pred
  pred_conv_k<<<181, 256, 0, stream>>>(t1, wpT, bp, pred);

  decode_k<<<8, 256, 0, stream>>>(pred, out, cls_i);
  nms_k<<<20, 256, 0, stream>>>(out, out + 7220, cls_i, out + 10830);
}

// Round 2
// 1043.032 us; speedup vs baseline: 1.4659x; 1.4659x over previous
//
#include <hip/hip_runtime.h>

#define N_BOX 1805
#define NPIX 361
#define NCLS 20

__device__ __forceinline__ float leakyf(float x){ return x > 0.f ? x : 0.1f*x; }
__device__ __forceinline__ float sigmoidf_(float x){ return 1.f/(1.f + expf(-x)); }

// ---------------- small transpose: dst[C][R] = src[R][C] ----------------
__global__ void transpose_k(const float* __restrict__ src, float* __restrict__ dst, int R, int C){
  int i = blockIdx.x*256 + threadIdx.x;
  if (i < R*C){ int r = i / C, c = i % C; dst[c*R + r] = src[i]; }
}

// ---------------- reorg path: leaky(conv1x1(feat2, wr)+br) -> reorg -> cat[0:256] ----------------
__global__ __launch_bounds__(256) void reorg_conv_k(const float* __restrict__ feat2,
    const float* __restrict__ wrT, const float* __restrict__ br, float* __restrict__ cat){
  int c  = threadIdx.x & 63;
  int pq = threadIdx.x >> 6;
  int pix = blockIdx.x*4 + pq;      // 0..1443
  int y = pix / 38, x = pix % 38;
  __shared__ float s_in[64][4];
  float acc = br[c];
  for (int cb = 0; cb < 512; cb += 64){
    __syncthreads();
    { int k = threadIdx.x >> 2, pp = threadIdx.x & 3;
      s_in[k][pp] = feat2[(cb + k)*1444 + blockIdx.x*4 + pp]; }
    __syncthreads();
    #pragma unroll
    for (int k = 0; k < 64; ++k)
      acc = fmaf(wrT[(cb+k)*64 + c], s_in[k][pq], acc);
  }
  float v = leakyf(acc);
  int co = ((y & 1)*2 + (x & 1))*64 + c;   // reorg channel mapping
  cat[co*NPIX + (y>>1)*19 + (x>>1)] = v;
}

// ---------------- generic 3x3 conv on 19x19, split-K partials ----------------
#define CO_TILE 16
#define CTHREADS 384
#define CI_CHUNK 8

__global__ __launch_bounds__(CTHREADS) void conv3x3_part_k(const float* __restrict__ in,
    const float* __restrict__ w, float* __restrict__ part, int Cin, int kchunk){
  const int Cout = 1024;
  int kc  = blockIdx.y;             // split-K index (8)
  int cob = blockIdx.x * CO_TILE;   // out-channel base
  int ci0 = kc * kchunk;
  __shared__ float tile[CI_CHUNK][441];   // padded 21x21 per channel
  int tid = threadIdx.x;
  int p = tid, py = p / 19, px = p % 19;
  float acc[CO_TILE];
  #pragma unroll
  for (int i = 0; i < CO_TILE; ++i) acc[i] = 0.f;

  for (int cc = 0; cc < kchunk; cc += CI_CHUNK){
    __syncthreads();
    for (int idx = tid; idx < CI_CHUNK*441; idx += CTHREADS){
      int c = idx / 441, r = idx % 441;
      int yy = r / 21 - 1, xx = r % 21 - 1;
      float v = 0.f;
      if ((unsigned)yy < 19u && (unsigned)xx < 19u)
        v = in[(ci0 + cc + c)*NPIX + yy*19 + xx];
      tile[c][r] = v;
    }
    __syncthreads();
    if (p < NPIX){
      #pragma unroll
      for (int c = 0; c < CI_CHUNK; ++c){
        float iv[9];
        #pragma unroll
        for (int dy = 0; dy < 3; ++dy)
          #pragma unroll
          for (int dx = 0; dx < 3; ++dx)
            iv[dy*3+dx] = tile[c][(py+dy)*21 + (px+dx)];
        const float* wb = w + ((size_t)cob * Cin + (ci0 + cc + c)) * 9;
        #pragma unroll
        for (int co = 0; co < CO_TILE; ++co){
          const float* wp = wb + (size_t)co * Cin * 9;   // uniform -> s_load
          #pragma unroll
          for (int t = 0; t < 9; ++t) acc[co] = fmaf(wp[t], iv[t], acc[co]);
        }
      }
    }
  }
  if (p < NPIX){
    #pragma unroll
    for (int co = 0; co < CO_TILE; ++co)
      part[(size_t)kc*Cout*NPIX + (cob+co)*NPIX + p] = acc[co];
  }
}

// ---------------- reduce split-K partials + bias + leaky ----------------
__global__ void reduce_k(const float* __restrict__ part, const float* __restrict__ bias,
                         float* __restrict__ out, int total, int do_leaky){
  int i = blockIdx.x*256 + threadIdx.x;
  if (i >= total) return;
  int co = i / NPIX;
  float s = bias[co];
  #pragma unroll
  for (int k = 0; k < 8; ++k) s += part[(size_t)k*total + i];
  out[i] = do_leaky ? leakyf(s) : s;
}

// ---------------- pred 1x1 conv: 1024 -> 125 ----------------
__global__ __launch_bounds__(256) void pred_conv_k(const float* __restrict__ t3,
    const float* __restrict__ wpT, const float* __restrict__ bp, float* __restrict__ pred){
  int c = threadIdx.x & 127, ph = threadIdx.x >> 7;
  int pix = blockIdx.x*2 + ph;
  __shared__ float s_in[64][2];
  float acc = 0.f;
  for (int cb = 0; cb < 1024; cb += 64){
    __syncthreads();
    if (threadIdx.x < 128){
      int k = threadIdx.x & 63, pp = threadIdx.x >> 6;
      int px2 = blockIdx.x*2 + pp;
      s_in[k][pp] = (px2 < NPIX) ? t3[(cb+k)*NPIX + px2] : 0.f;
    }
    __syncthreads();
    if (c < 125){
      #pragma unroll
      for (int k = 0; k < 64; ++k)
        acc = fmaf(wpT[(cb+k)*125 + c], s_in[k][ph], acc);
    }
  }
  if (c < 125 && pix < NPIX) pred[c*NPIX + pix] = acc + bp[c];
}

// ---------------- decode boxes / scores / argmax (+ zero class counters) ----------------
__device__ const float ANCW[5] = {1.19f, 2.79f, 4.53f, 8.06f, 10.32f};
__device__ const float ANCH_[5] = {1.98f, 4.59f, 8.92f, 5.29f, 10.65f};

__global__ void decode_k(const float* __restrict__ pred, float* __restrict__ out,
                         int* __restrict__ cls_i, int* __restrict__ cnt){
  int n = blockIdx.x*256 + threadIdx.x;
  if (blockIdx.x == 0 && threadIdx.x < NCLS) cnt[threadIdx.x] = 0;
  if (n >= N_BOX) return;
  int p = n / 5, a = n % 5;
  float conf = pred[a*NPIX + p];
  float cl[20]; float m = -1e30f;
  #pragma unroll
  for (int k = 0; k < 20; ++k){ cl[k] = pred[(5 + a*20 + k)*NPIX + p]; m = fmaxf(m, cl[k]); }
  float s = 0.f;
  #pragma unroll
  for (int k = 0; k < 20; ++k){ cl[k] = expf(cl[k]-m); s += cl[k]; }
  int bi = 0; float bv = cl[0];
  #pragma unroll
  for (int k = 1; k < 20; ++k) if (cl[k] > bv){ bv = cl[k]; bi = k; }
  float score = sigmoidf_(conf) * (bv / s);
  float tx = pred[(105 + a*4 + 0)*NPIX + p];
  float ty = pred[(105 + a*4 + 1)*NPIX + p];
  float tw = pred[(105 + a*4 + 2)*NPIX + p];
  float th = pred[(105 + a*4 + 3)*NPIX + p];
  float gx = (float)(p % 19), gy = (float)(p / 19);
  float cx = (sigmoidf_(tx) + gx) * 32.f;
  float cy = (sigmoidf_(ty) + gy) * 32.f;
  float bw = expf(tw) * ANCW[a] * 32.f;
  float bh = expf(th) * ANCH_[a] * 32.f;
  float x1 = fminf(fmaxf((cx - 0.5f*bw) / 608.f, 0.f), 1.f);
  float y1 = fminf(fmaxf((cy - 0.5f*bh) / 608.f, 0.f), 1.f);
  float x2 = fminf(fmaxf((cx + 0.5f*bw) / 608.f, 0.f), 1.f);
  float y2 = fminf(fmaxf((cy + 0.5f*bh) / 608.f, 0.f), 1.f);
  out[n*4+0]=x1; out[n*4+1]=y1; out[n*4+2]=x2; out[n*4+3]=y2;
  out[7220 + n]  = score;
  out[9025 + n]  = (float)bi;
  out[10830 + n] = 0.f;          // keep init
  cls_i[n] = bi;
}

// ---------------- per-class rank (score desc, idx asc) ----------------
__global__ __launch_bounds__(256) void rank_k(const float* __restrict__ scores,
    const int* __restrict__ cls_i, int* __restrict__ ord, int* __restrict__ cnt){
  __shared__ float s_sc[N_BOX];
  __shared__ short s_cl[N_BOX];
  int tid = threadIdx.x;
  for (int j = tid; j < N_BOX; j += 256){ s_sc[j] = scores[j]; s_cl[j] = (short)cls_i[j]; }
  __syncthreads();
  int i = blockIdx.x*256 + tid;
  if (i >= N_BOX) return;
  float si = s_sc[i]; int ci = s_cl[i];
  int r = 0;
  #pragma unroll 8
  for (int j = 0; j < N_BOX; ++j){
    float sj = s_sc[j];
    int hit = (s_cl[j] == (short)ci) & ((sj > si) | ((sj == si) & (j < i)));
    r += hit;
  }
  ord[ci*N_BOX + r] = i;
  atomicAdd(&cnt[ci], 1);
}

// ---------------- per-class NMS on compacted sorted list ----------------
__global__ __launch_bounds__(256) void nms2_k(const float* __restrict__ boxes,
    const int* __restrict__ ord, const int* __restrict__ cnt, float* __restrict__ keep){
  __shared__ float X1[N_BOX], Y1[N_BOX], X2[N_BOX], Y2[N_BOX], AR[N_BOX];
  __shared__ unsigned char SUP[N_BOX];
  __shared__ int IDX[N_BOX];
  int c = blockIdx.x, tid = threadIdx.x;
  int n = cnt[c];
  for (int t = tid; t < n; t += 256){
    int bi = ord[c*N_BOX + t];
    float x1 = boxes[bi*4+0], y1 = boxes[bi*4+1], x2 = boxes[bi*4+2], y2 = boxes[bi*4+3];
    X1[t]=x1; Y1[t]=y1; X2[t]=x2; Y2[t]=y2; AR[t]=(x2-x1)*(y2-y1);
    SUP[t]=0; IDX[t]=bi;
  }
  __syncthreads();
  for (int k = 0; k < n; ++k){
    if (!SUP[k]){
      if (tid == 0) keep[IDX[k]] = 1.f;
      float ax1=X1[k], ay1=Y1[k], ax2=X2[k], ay2=Y2[k], areaA=AR[k];
      for (int j = k+1+tid; j < n; j += 256){
        float iw = fmaxf(1e-10f, fminf(ax2,X2[j]) - fmaxf(ax1,X1[j]));
        float ih = fmaxf(1e-10f, fminf(ay2,Y2[j]) - fmaxf(ay1,Y1[j]));
        float inter = iw*ih;
        float iou = inter / (areaA + AR[j] - inter);
        if (iou > 0.5f) SUP[j] = 1;
      }
    }
    __syncthreads();
  }
}

extern "C" void kernel_launch(void* const* d_in, const int* in_sizes, int n_in,
                              void* d_out, int out_size, void* d_ws, size_t ws_size,
                              hipStream_t stream){
  const float* feat2 = (const float*)d_in[0];   // (512,38,38)
  const float* feat3 = (const float*)d_in[1];   // (1024,19,19)
  const float* w1a = (const float*)d_in[2];
  const float* b1a = (const float*)d_in[3];
  const float* w1b = (const float*)d_in[4];
  const float* b1b = (const float*)d_in[5];
  const float* wr  = (const float*)d_in[6];
  const float* br  = (const float*)d_in[7];
  const float* w2  = (const float*)d_in[8];
  const float* b2  = (const float*)d_in[9];
  const float* wp  = (const float*)d_in[10];
  const float* bp  = (const float*)d_in[11];
  float* out = (float*)d_out;
  float* ws  = (float*)d_ws;

  float* cat  = ws;                    // 1280*361
  float* t1   = cat + 1280*NPIX;       // 1024*361
  float* part = t1 + 1024*NPIX;        // 8*1024*361
  float* pred = part + 8*1024*NPIX;    // 125*361
  float* wrT  = pred + 125*NPIX;       // 512*64
  float* wpT  = wrT + 512*64;          // 1024*125
  int*   cls_i = (int*)(wpT + 1024*125);
  int*   ord   = cls_i + N_BOX;        // 20*1805
  int*   cnt   = ord + NCLS*N_BOX;     // 20

  transpose_k<<<(64*512 + 255)/256, 256, 0, stream>>>(wr, wrT, 64, 512);
  transpose_k<<<(125*1024 + 255)/256, 256, 0, stream>>>(wp, wpT, 125, 1024);
  reorg_conv_k<<<361, 256, 0, stream>>>(feat2, wrT, br, cat);

  dim3 cg(64, 8);
  conv3x3_part_k<<<cg, CTHREADS, 0, stream>>>(feat3, w1a, part, 1024, 128);
  reduce_k<<<(1024*NPIX + 255)/256, 256, 0, stream>>>(part, b1a, t1, 1024*NPIX, 1);
  conv3x3_part_k<<<cg, CTHREADS, 0, stream>>>(t1, w1b, part, 1024, 128);
  reduce_k<<<(1024*NPIX + 255)/256, 256, 0, stream>>>(part, b1b, cat + 256*NPIX, 1024*NPIX, 1);
  conv3x3_part_k<<<cg, CTHREADS, 0, stream>>>(cat, w2, part, 1280, 160);
  reduce_k<<<(1024*NPIX + 255)/256, 256, 0, stream>>>(part, b2, t1, 1024*NPIX, 1);
  pred_conv_k<<<181, 256, 0, stream>>>(t1, wpT, bp, pred);

  decode_k<<<8, 256, 0, stream>>>(pred, out, cls_i, cnt);
  rank_k<<<8, 256, 0, stream>>>(out + 7220, cls_i, ord, cnt);
  nms2_k<<<NCLS, 256, 0, stream>>>(out, ord, cnt, out + 10830);
}

// Round 3
// 696.788 us; speedup vs baseline: 2.1943x; 1.4969x over previous
//
#include <hip/hip_runtime.h>

#define N_BOX 1805
#define NPIX 361
#define NCLS 20
#define SPLITK 16

__device__ __forceinline__ float leakyf(float x){ return x > 0.f ? x : 0.1f*x; }
__device__ __forceinline__ float sigmoidf_(float x){ return 1.f/(1.f + expf(-x)); }

// ---------------- small transpose: dst[C][R] = src[R][C] ----------------
__global__ void transpose_k(const float* __restrict__ src, float* __restrict__ dst, int R, int C){
  int i = blockIdx.x*256 + threadIdx.x;
  if (i < R*C){ int r = i / C, c = i % C; dst[c*R + r] = src[i]; }
}

// ---------------- reorg path: leaky(conv1x1(feat2, wr)+br) -> reorg -> cat[0:256] ----------------
__global__ __launch_bounds__(256) void reorg_conv_k(const float* __restrict__ feat2,
    const float* __restrict__ wrT, const float* __restrict__ br, float* __restrict__ cat){
  int c  = threadIdx.x & 63;
  int pq = threadIdx.x >> 6;
  int pix = blockIdx.x*4 + pq;      // 0..1443
  int y = pix / 38, x = pix % 38;
  __shared__ float s_in[64][4];
  float acc = br[c];
  for (int cb = 0; cb < 512; cb += 64){
    __syncthreads();
    { int k = threadIdx.x >> 2, pp = threadIdx.x & 3;
      s_in[k][pp] = feat2[(cb + k)*1444 + blockIdx.x*4 + pp]; }
    __syncthreads();
    #pragma unroll
    for (int k = 0; k < 64; ++k)
      acc = fmaf(wrT[(cb+k)*64 + c], s_in[k][pq], acc);
  }
  float v = leakyf(acc);
  int co = ((y & 1)*2 + (x & 1))*64 + c;   // reorg channel mapping
  cat[co*NPIX + (y>>1)*19 + (x>>1)] = v;
}

// ---------------- 3x3 conv as im2col SGEMM, split-K partials ----------------
// C[co][p] = sum_k W[co][k] * X[k][p],  k = ci*9 + (dy*3+dx)
// block: 256 thr = 16x16, each thread 8x8 of a 128(co) x 128(px) tile
// grid: (8 co-blocks, 3 px-blocks, SPLITK)
__global__ __launch_bounds__(256) void conv3x3_gemm_k(const float* __restrict__ in,
    const float* __restrict__ w, float* __restrict__ part, int Cin){
  const int Cout = 1024;
  int cob = blockIdx.x * 128;
  int px0 = blockIdx.y * 128;
  int ks  = blockIdx.z;
  int ciPer = Cin / SPLITK;          // 64 (Cin=1024) or 80 (Cin=1280)
  int ci0base = ks * ciPer;
  int tid = threadIdx.x;
  int tx = tid & 15, ty = tid >> 4;

  __shared__ float sA[36][132];      // [k][co]
  __shared__ float sB[36][132];      // [k][px]

  float acc[8][8];
  #pragma unroll
  for (int i = 0; i < 8; ++i)
    #pragma unroll
    for (int j = 0; j < 8; ++j) acc[i][j] = 0.f;

  const int nstage = ciPer >> 2;     // 4 ci per stage -> 36 k rows
  for (int st = 0; st < nstage; ++st){
    int ci0 = ci0base + st*4;
    __syncthreads();
    // stage A: sA[k][co] = w[(cob+co)*Cin*9 + ci0*9 + k]   (k contiguous per co)
    #pragma unroll
    for (int i = 0; i < 18; ++i){
      int idx = tid + i*256;                 // 0..4607
      int co = idx / 36, k = idx - co*36;
      sA[k][co] = w[(size_t)(cob+co)*Cin*9 + ci0*9 + k];
    }
    // stage B (im2col with boundary masks)
    #pragma unroll
    for (int i = 0; i < 18; ++i){
      int idx = tid + i*256;                 // 0..4607
      int row = idx >> 7, j = idx & 127;     // row 0..35
      int c = row / 9, t = row - c*9;
      int dy = t / 3, dx = t - dy*3;
      int p = px0 + j;
      int py = p / 19, px = p - py*19;
      int yy = py + dy - 1, xx = px + dx - 1;
      float v = 0.f;
      if (p < NPIX && (unsigned)yy < 19u && (unsigned)xx < 19u)
        v = in[(ci0 + c)*NPIX + yy*19 + xx];
      sB[row][j] = v;
    }
    __syncthreads();
    #pragma unroll 6
    for (int k = 0; k < 36; ++k){
      float4 A1 = *(const float4*)&sA[k][ty*8];
      float4 A2 = *(const float4*)&sA[k][ty*8 + 4];
      float4 B1 = *(const float4*)&sB[k][tx*8];
      float4 B2 = *(const float4*)&sB[k][tx*8 + 4];
      float a[8] = {A1.x,A1.y,A1.z,A1.w,A2.x,A2.y,A2.z,A2.w};
      float b[8] = {B1.x,B1.y,B1.z,B1.w,B2.x,B2.y,B2.z,B2.w};
      #pragma unroll
      for (int i = 0; i < 8; ++i)
        #pragma unroll
        for (int j = 0; j < 8; ++j)
          acc[i][j] = fmaf(a[i], b[j], acc[i][j]);
    }
  }
  // store partials
  #pragma unroll
  for (int i = 0; i < 8; ++i){
    int co = cob + ty*8 + i;
    #pragma unroll
    for (int j = 0; j < 8; ++j){
      int p = px0 + tx*8 + j;
      if (p < NPIX) part[((size_t)ks*Cout + co)*NPIX + p] = acc[i][j];
    }
  }
}

// ---------------- reduce split-K partials + bias + leaky ----------------
__global__ void reduce16_k(const float* __restrict__ part, const float* __restrict__ bias,
                           float* __restrict__ out, int do_leaky){
  int i = blockIdx.x*256 + threadIdx.x;
  if (i >= 1024*NPIX) return;
  int co = i / NPIX;
  float s = bias[co];
  #pragma unroll
  for (int k = 0; k < SPLITK; ++k) s += part[(size_t)k*1024*NPIX + i];
  out[i] = do_leaky ? leakyf(s) : s;
}

// ---------------- pred 1x1 conv: 1024 -> 125 ----------------
__global__ __launch_bounds__(256) void pred_conv_k(const float* __restrict__ t3,
    const float* __restrict__ wpT, const float* __restrict__ bp, float* __restrict__ pred){
  int c = threadIdx.x & 127, ph = threadIdx.x >> 7;
  int pix = blockIdx.x*2 + ph;
  __shared__ float s_in[64][2];
  float acc = 0.f;
  for (int cb = 0; cb < 1024; cb += 64){
    __syncthreads();
    if (threadIdx.x < 128){
      int k = threadIdx.x & 63, pp = threadIdx.x >> 6;
      int px2 = blockIdx.x*2 + pp;
      s_in[k][pp] = (px2 < NPIX) ? t3[(cb+k)*NPIX + px2] : 0.f;
    }
    __syncthreads();
    if (c < 125){
      #pragma unroll
      for (int k = 0; k < 64; ++k)
        acc = fmaf(wpT[(cb+k)*125 + c], s_in[k][ph], acc);
    }
  }
  if (c < 125 && pix < NPIX) pred[c*NPIX + pix] = acc + bp[c];
}

// ---------------- decode boxes / scores / argmax (+ zero class counters) ----------------
__device__ const float ANCW[5] = {1.19f, 2.79f, 4.53f, 8.06f, 10.32f};
__device__ const float ANCH_[5] = {1.98f, 4.59f, 8.92f, 5.29f, 10.65f};

__global__ void decode_k(const float* __restrict__ pred, float* __restrict__ out,
                         int* __restrict__ cls_i, int* __restrict__ cnt){
  int n = blockIdx.x*256 + threadIdx.x;
  if (blockIdx.x == 0 && threadIdx.x < NCLS) cnt[threadIdx.x] = 0;
  if (n >= N_BOX) return;
  int p = n / 5, a = n % 5;
  float conf = pred[a*NPIX + p];
  float cl[20]; float m = -1e30f;
  #pragma unroll
  for (int k = 0; k < 20; ++k){ cl[k] = pred[(5 + a*20 + k)*NPIX + p]; m = fmaxf(m, cl[k]); }
  float s = 0.f;
  #pragma unroll
  for (int k = 0; k < 20; ++k){ cl[k] = expf(cl[k]-m); s += cl[k]; }
  int bi = 0; float bv = cl[0];
  #pragma unroll
  for (int k = 1; k < 20; ++k) if (cl[k] > bv){ bv = cl[k]; bi = k; }
  float score = sigmoidf_(conf) * (bv / s);
  float tx = pred[(105 + a*4 + 0)*NPIX + p];
  float ty = pred[(105 + a*4 + 1)*NPIX + p];
  float tw = pred[(105 + a*4 + 2)*NPIX + p];
  float th = pred[(105 + a*4 + 3)*NPIX + p];
  float gx = (float)(p % 19), gy = (float)(p / 19);
  float cx = (sigmoidf_(tx) + gx) * 32.f;
  float cy = (sigmoidf_(ty) + gy) * 32.f;
  float bw = expf(tw) * ANCW[a] * 32.f;
  float bh = expf(th) * ANCH_[a] * 32.f;
  float x1 = fminf(fmaxf((cx - 0.5f*bw) / 608.f, 0.f), 1.f);
  float y1 = fminf(fmaxf((cy - 0.5f*bh) / 608.f, 0.f), 1.f);
  float x2 = fminf(fmaxf((cx + 0.5f*bw) / 608.f, 0.f), 1.f);
  float y2 = fminf(fmaxf((cy + 0.5f*bh) / 608.f, 0.f), 1.f);
  out[n*4+0]=x1; out[n*4+1]=y1; out[n*4+2]=x2; out[n*4+3]=y2;
  out[7220 + n]  = score;
  out[9025 + n]  = (float)bi;
  out[10830 + n] = 0.f;          // keep init
  cls_i[n] = bi;
}

// ---------------- per-class rank (score desc, idx asc) ----------------
__global__ __launch_bounds__(256) void rank_k(const float* __restrict__ scores,
    const int* __restrict__ cls_i, int* __restrict__ ord, int* __restrict__ cnt){
  __shared__ float s_sc[N_BOX];
  __shared__ short s_cl[N_BOX];
  int tid = threadIdx.x;
  for (int j = tid; j < N_BOX; j += 256){ s_sc[j] = scores[j]; s_cl[j] = (short)cls_i[j]; }
  __syncthreads();
  int i = blockIdx.x*256 + tid;
  if (i >= N_BOX) return;
  float si = s_sc[i]; int ci = s_cl[i];
  int r = 0;
  #pragma unroll 8
  for (int j = 0; j < N_BOX; ++j){
    float sj = s_sc[j];
    int hit = (s_cl[j] == (short)ci) & ((sj > si) | ((sj == si) & (j < i)));
    r += hit;
  }
  ord[ci*N_BOX + r] = i;
  atomicAdd(&cnt[ci], 1);
}

// ---------------- per-class NMS on compacted sorted list ----------------
__global__ __launch_bounds__(256) void nms2_k(const float* __restrict__ boxes,
    const int* __restrict__ ord, const int* __restrict__ cnt, float* __restrict__ keep){
  __shared__ float X1[N_BOX], Y1[N_BOX], X2[N_BOX], Y2[N_BOX], AR[N_BOX];
  __shared__ unsigned char SUP[N_BOX];
  __shared__ int IDX[N_BOX];
  int c = blockIdx.x, tid = threadIdx.x;
  int n = cnt[c];
  for (int t = tid; t < n; t += 256){
    int bi = ord[c*N_BOX + t];
    float x1 = boxes[bi*4+0], y1 = boxes[bi*4+1], x2 = boxes[bi*4+2], y2 = boxes[bi*4+3];
    X1[t]=x1; Y1[t]=y1; X2[t]=x2; Y2[t]=y2; AR[t]=(x2-x1)*(y2-y1);
    SUP[t]=0; IDX[t]=bi;
  }
  __syncthreads();
  for (int k = 0; k < n; ++k){
    if (!SUP[k]){
      if (tid == 0) keep[IDX[k]] = 1.f;
      float ax1=X1[k], ay1=Y1[k], ax2=X2[k], ay2=Y2[k], areaA=AR[k];
      for (int j = k+1+tid; j < n; j += 256){
        float iw = fmaxf(1e-10f, fminf(ax2,X2[j]) - fmaxf(ax1,X1[j]));
        float ih = fmaxf(1e-10f, fminf(ay2,Y2[j]) - fmaxf(ay1,Y1[j]));
        float inter = iw*ih;
        float iou = inter / (areaA + AR[j] - inter);
        if (iou > 0.5f) SUP[j] = 1;
      }
    }
    __syncthreads();
  }
}

extern "C" void kernel_launch(void* const* d_in, const int* in_sizes, int n_in,
                              void* d_out, int out_size, void* d_ws, size_t ws_size,
                              hipStream_t stream){
  const float* feat2 = (const float*)d_in[0];   // (512,38,38)
  const float* feat3 = (const float*)d_in[1];   // (1024,19,19)
  const float* w1a = (const float*)d_in[2];
  const float* b1a = (const float*)d_in[3];
  const float* w1b = (const float*)d_in[4];
  const float* b1b = (const float*)d_in[5];
  const float* wr  = (const float*)d_in[6];
  const float* br  = (const float*)d_in[7];
  const float* w2  = (const float*)d_in[8];
  const float* b2  = (const float*)d_in[9];
  const float* wp  = (const float*)d_in[10];
  const float* bp  = (const float*)d_in[11];
  float* out = (float*)d_out;
  float* ws  = (float*)d_ws;

  float* cat  = ws;                        // 1280*361
  float* t1   = cat + 1280*NPIX;           // 1024*361
  float* part = t1 + 1024*NPIX;            // SPLITK*1024*361
  float* pred = part + (size_t)SPLITK*1024*NPIX;  // 125*361
  float* wrT  = pred + 125*NPIX;           // 512*64
  float* wpT  = wrT + 512*64;              // 1024*125
  int*   cls_i = (int*)(wpT + 1024*125);
  int*   ord   = cls_i + N_BOX;            // 20*1805
  int*   cnt   = ord + NCLS*N_BOX;         // 20

  transpose_k<<<(64*512 + 255)/256, 256, 0, stream>>>(wr, wrT, 64, 512);
  transpose_k<<<(125*1024 + 255)/256, 256, 0, stream>>>(wp, wpT, 125, 1024);
  reorg_conv_k<<<361, 256, 0, stream>>>(feat2, wrT, br, cat);

  dim3 cg(8, 3, SPLITK);
  // conv1: feat3 (1024) -> t1
  conv3x3_gemm_k<<<cg, 256, 0, stream>>>(feat3, w1a, part, 1024);
  reduce16_k<<<(1024*NPIX + 255)/256, 256, 0, stream>>>(part, b1a, t1, 1);
  // conv2: t1 (1024) -> cat[256:1280]
  conv3x3_gemm_k<<<cg, 256, 0, stream>>>(t1, w1b, part, 1024);
  reduce16_k<<<(1024*NPIX + 255)/256, 256, 0, stream>>>(part, b1b, cat + 256*NPIX, 1);
  // conv3: cat (1280) -> t1
  conv3x3_gemm_k<<<cg, 256, 0, stream>>>(cat, w2, part, 1280);
  reduce16_k<<<(1024*NPIX + 255)/256, 256, 0, stream>>>(part, b2, t1, 1);
  // pred 1x1: t1 -> pred
  pred_conv_k<<<181, 256, 0, stream>>>(t1, wpT, bp, pred);

  decode_k<<<8, 256, 0, stream>>>(pred, out, cls_i, cnt);
  rank_k<<<8, 256, 0, stream>>>(out + 7220, cls_i, ord, cnt);
  nms2_k<<<NCLS, 256, 0, stream>>>(out, ord, cnt, out + 10830);
}

// Round 4
// 373.721 us; speedup vs baseline: 4.0912x; 1.8645x over previous
//
#include <hip/hip_runtime.h>

typedef _Float16 f16;
typedef _Float16 f16x8 __attribute__((ext_vector_type(8)));
typedef float f32x4 __attribute__((ext_vector_type(4)));

#define N_BOX 1805
#define NPIX 361
#define NCLS 20

__device__ __forceinline__ float leakyf(float x){ return x > 0.f ? x : 0.1f*x; }
__device__ __forceinline__ float sigmoidf_(float x){ return 1.f/(1.f + expf(-x)); }

// ---------------- small transpose: dst[C][R] = src[R][C] (fp32, for wrT/wpT) ----------------
__global__ void transpose_k(const float* __restrict__ src, float* __restrict__ dst, int R, int C){
  int i = blockIdx.x*256 + threadIdx.x;
  if (i < R*C){ int r = i / C, c = i % C; dst[c*R + r] = src[i]; }
}

// ---------------- weight prep: w[Cout][Cin][9] fp32 -> whi/wlo[Cout][9][Cin] f16, scaled x64 ----------------
__global__ void wprep_k(const float* __restrict__ w, f16* __restrict__ whi, f16* __restrict__ wlo,
                        int Cin, int total){
  int i = blockIdx.x*256 + threadIdx.x;   // over Cout*Cin
  if (i >= total) return;
  int co = i / Cin, ci = i - co*Cin;
  const float* src = w + (size_t)i*9;     // [co][ci][0..9)
  int K9 = 9*Cin;
  size_t dbase = (size_t)co*K9 + ci;
  #pragma unroll
  for (int t = 0; t < 9; ++t){
    float v = src[t]*64.f;
    f16 hi = (f16)v;
    f16 lo = (f16)(v - (float)hi);
    whi[dbase + (size_t)t*Cin] = hi;
    wlo[dbase + (size_t)t*Cin] = lo;
  }
}

// ---------------- act1 prep: feat3[1024][361] fp32 -> a1hi/a1lo[361][1024] f16 ----------------
__global__ void act1prep_k(const float* __restrict__ feat3, f16* __restrict__ ah, f16* __restrict__ al){
  int i = blockIdx.x*256 + threadIdx.x;  // over 361*1024
  if (i >= NPIX*1024) return;
  int p = i >> 10, c = i & 1023;
  float v = feat3[c*NPIX + p];
  f16 hi = (f16)v; f16 lo = (f16)(v - (float)hi);
  ah[i] = hi; al[i] = lo;
}

// ---------------- reorg path: leaky(conv1x1(feat2, wr)+br) -> reorg -> cat[ ][0:256) f16 hi/lo ----------------
__global__ __launch_bounds__(256) void reorg_conv_k(const float* __restrict__ feat2,
    const float* __restrict__ wrT, const float* __restrict__ br,
    f16* __restrict__ cath, f16* __restrict__ catl){
  int c  = threadIdx.x & 63;
  int pq = threadIdx.x >> 6;
  int pix = blockIdx.x*4 + pq;      // 0..1443
  int y = pix / 38, x = pix % 38;
  __shared__ float s_in[64][4];
  float acc = br[c];
  for (int cb = 0; cb < 512; cb += 64){
    __syncthreads();
    { int k = threadIdx.x >> 2, pp = threadIdx.x & 3;
      s_in[k][pp] = feat2[(cb + k)*1444 + blockIdx.x*4 + pp]; }
    __syncthreads();
    #pragma unroll
    for (int k = 0; k < 64; ++k)
      acc = fmaf(wrT[(cb+k)*64 + c], s_in[k][pq], acc);
  }
  float v = leakyf(acc);
  int co = ((y & 1)*2 + (x & 1))*64 + c;   // reorg channel mapping
  int p = (y>>1)*19 + (x>>1);
  f16 hi = (f16)v; f16 lo = (f16)(v - (float)hi);
  size_t o = (size_t)p*1280 + co;
  cath[o] = hi; catl[o] = lo;
}

// ---------------- 3x3 conv as MFMA GEMM (f16 2-term split, 3 passes), split-K partials ----------------
// C[co][p] = sum_k' W[co][k'] * X[k'][p], k' = t*Cin + ci
// block 256 thr = 4 waves (2x2), tile 128(co) x 128(px), BK=32
__global__ __launch_bounds__(256) void conv_mfma_k(
    const f16* __restrict__ whi, const f16* __restrict__ wlo,
    const f16* __restrict__ ahi, const f16* __restrict__ alo,
    float* __restrict__ part, int Cin, int chunks, int cpt)
{
  const int K9 = 9*Cin;
  int cob = blockIdx.x * 128;
  int px0 = blockIdx.y * 128;
  int ks  = blockIdx.z;
  int kc0 = ks * chunks;
  int tid = threadIdx.x;

  __shared__ f16 sAh[128*32], sAl[128*32], sBh[128*32], sBl[128*32];

  // staging assignment: 2 threads per row, 16 f16 (32B) per thread per buffer
  int r = tid >> 1, h = tid & 1;
  int wb0 = ((r*64 + h*32)      ) ^ ((r&7)<<4);
  int wb1 = ((r*64 + h*32 + 16) ) ^ ((r&7)<<4);
  const f16* wArowh = whi + (size_t)(cob + r)*K9 + h*16;
  const f16* wArowl = wlo + (size_t)(cob + r)*K9 + h*16;
  int p = px0 + r;
  int py = p / 19, px = p - py*19;

  // fragment addressing
  int lane = tid & 63, wid = tid >> 6;
  int lrow = lane & 15, lgrp = lane >> 4;
  int wr = wid >> 1, wc = wid & 1;
  int swz = (lrow & 7) << 4;
  int aoff[4], boff[4];
  #pragma unroll
  for (int m = 0; m < 4; ++m){
    int rA = wr*64 + m*16 + lrow;
    aoff[m] = (rA*64 + lgrp*16) ^ swz;
    int rB = wc*64 + m*16 + lrow;
    boff[m] = (rB*64 + lgrp*16) ^ swz;
  }

  f32x4 acc[4][4] = {};

  for (int kc = kc0; kc < kc0 + chunks; ++kc){
    int t = kc / cpt;                   // tap 0..8
    int ci0 = (kc - t*cpt) * 32;
    int dy = t / 3, dx = t - dy*3;
    int yy = py + dy - 1, xx = px + dx - 1;
    bool bvalid = (p < NPIX) && ((unsigned)yy < 19u) && ((unsigned)xx < 19u);

    // prefetch (registers) — overlaps previous iteration's MFMA
    f16x8 a0 = *(const f16x8*)(wArowh + (size_t)kc*32);
    f16x8 a1 = *(const f16x8*)(wArowh + (size_t)kc*32 + 8);
    f16x8 a2 = *(const f16x8*)(wArowl + (size_t)kc*32);
    f16x8 a3 = *(const f16x8*)(wArowl + (size_t)kc*32 + 8);
    f16x8 b0 = {}, b1 = {}, b2 = {}, b3 = {};
    if (bvalid){
      const f16* bh_src = ahi + (size_t)(yy*19+xx)*Cin + ci0 + h*16;
      const f16* bl_src = alo + (size_t)(yy*19+xx)*Cin + ci0 + h*16;
      b0 = *(const f16x8*)(bh_src);
      b1 = *(const f16x8*)(bh_src + 8);
      b2 = *(const f16x8*)(bl_src);
      b3 = *(const f16x8*)(bl_src + 8);
    }
    __syncthreads();
    *(f16x8*)((char*)sAh + wb0) = a0; *(f16x8*)((char*)sAh + wb1) = a1;
    *(f16x8*)((char*)sAl + wb0) = a2; *(f16x8*)((char*)sAl + wb1) = a3;
    *(f16x8*)((char*)sBh + wb0) = b0; *(f16x8*)((char*)sBh + wb1) = b1;
    *(f16x8*)((char*)sBl + wb0) = b2; *(f16x8*)((char*)sBl + wb1) = b3;
    __syncthreads();

    f16x8 bh[4], bl[4];
    #pragma unroll
    for (int n = 0; n < 4; ++n){
      bh[n] = *(const f16x8*)((char*)sBh + boff[n]);
      bl[n] = *(const f16x8*)((char*)sBl + boff[n]);
    }
    #pragma unroll
    for (int m = 0; m < 4; ++m){
      f16x8 ah = *(const f16x8*)((char*)sAh + aoff[m]);
      f16x8 al = *(const f16x8*)((char*)sAl + aoff[m]);
      #pragma unroll
      for (int n = 0; n < 4; ++n){
        acc[m][n] = __builtin_amdgcn_mfma_f32_16x16x32_f16(ah, bh[n], acc[m][n], 0,0,0);
        acc[m][n] = __builtin_amdgcn_mfma_f32_16x16x32_f16(ah, bl[n], acc[m][n], 0,0,0);
        acc[m][n] = __builtin_amdgcn_mfma_f32_16x16x32_f16(al, bh[n], acc[m][n], 0,0,0);
      }
    }
  }

  // store partials: D layout col=lane&15 (px), row=(lane>>4)*4+reg (co)
  #pragma unroll
  for (int m = 0; m < 4; ++m){
    #pragma unroll
    for (int n = 0; n < 4; ++n){
      int pp = px0 + wc*64 + n*16 + lrow;
      if (pp < NPIX){
        int co = cob + wr*64 + m*16 + lgrp*4;
        size_t base = ((size_t)ks*1024 + co)*NPIX + pp;
        part[base          ] = acc[m][n][0];
        part[base +   NPIX ] = acc[m][n][1];
        part[base + 2*NPIX ] = acc[m][n][2];
        part[base + 3*NPIX ] = acc[m][n][3];
      }
    }
  }
}

// ---------------- reduce split-K partials (x1/64) + bias + leaky -> transposed f16 hi/lo ----------------
__global__ void reduce16v_k(const float* __restrict__ part, const float* __restrict__ bias,
                            f16* __restrict__ dhi, f16* __restrict__ dlo,
                            int Cstride, int Coff, int splitk){
  int i = blockIdx.x*256 + threadIdx.x;
  if (i >= 1024*NPIX) return;
  int co = i / NPIX, p = i - co*NPIX;
  float s = 0.f;
  for (int k = 0; k < splitk; ++k) s += part[(size_t)k*1024*NPIX + i];
  float v = leakyf(s*0.015625f + bias[co]);
  f16 hi = (f16)v;
  f16 lo = (f16)(v - (float)hi);
  size_t o = (size_t)p*Cstride + Coff + co;
  dhi[o] = hi; dlo[o] = lo;
}

// ---------------- pred 1x1 conv: act3[361][1024] (hi+lo) -> 125 ----------------
__global__ __launch_bounds__(256) void pred_conv_k(const f16* __restrict__ a3h, const f16* __restrict__ a3l,
    const float* __restrict__ wpT, const float* __restrict__ bp, float* __restrict__ pred){
  int c = threadIdx.x & 127, ph = threadIdx.x >> 7;
  int pix = blockIdx.x*2 + ph;
  __shared__ float s_in[64][2];
  float acc = 0.f;
  for (int cb = 0; cb < 1024; cb += 64){
    __syncthreads();
    if (threadIdx.x < 128){
      int k = threadIdx.x & 63, pp = threadIdx.x >> 6;
      int px2 = blockIdx.x*2 + pp;
      float v = 0.f;
      if (px2 < NPIX){
        size_t o = (size_t)px2*1024 + cb + k;
        v = (float)a3h[o] + (float)a3l[o];
      }
      s_in[k][pp] = v;
    }
    __syncthreads();
    if (c < 125){
      #pragma unroll
      for (int k = 0; k < 64; ++k)
        acc = fmaf(wpT[(cb+k)*125 + c], s_in[k][ph], acc);
    }
  }
  if (c < 125 && pix < NPIX) pred[c*NPIX + pix] = acc + bp[c];
}

// ---------------- decode boxes / scores / argmax (+ zero class counters) ----------------
__device__ const float ANCW[5] = {1.19f, 2.79f, 4.53f, 8.06f, 10.32f};
__device__ const float ANCH_[5] = {1.98f, 4.59f, 8.92f, 5.29f, 10.65f};

__global__ void decode_k(const float* __restrict__ pred, float* __restrict__ out,
                         int* __restrict__ cls_i, int* __restrict__ cnt){
  int n = blockIdx.x*256 + threadIdx.x;
  if (blockIdx.x == 0 && threadIdx.x < NCLS) cnt[threadIdx.x] = 0;
  if (n >= N_BOX) return;
  int p = n / 5, a = n % 5;
  float conf = pred[a*NPIX + p];
  float cl[20]; float m = -1e30f;
  #pragma unroll
  for (int k = 0; k < 20; ++k){ cl[k] = pred[(5 + a*20 + k)*NPIX + p]; m = fmaxf(m, cl[k]); }
  float s = 0.f;
  #pragma unroll
  for (int k = 0; k < 20; ++k){ cl[k] = expf(cl[k]-m); s += cl[k]; }
  int bi = 0; float bv = cl[0];
  #pragma unroll
  for (int k = 1; k < 20; ++k) if (cl[k] > bv){ bv = cl[k]; bi = k; }
  float score = sigmoidf_(conf) * (bv / s);
  float tx = pred[(105 + a*4 + 0)*NPIX + p];
  float ty = pred[(105 + a*4 + 1)*NPIX + p];
  float tw = pred[(105 + a*4 + 2)*NPIX + p];
  float th = pred[(105 + a*4 + 3)*NPIX + p];
  float gx = (float)(p % 19), gy = (float)(p / 19);
  float cx = (sigmoidf_(tx) + gx) * 32.f;
  float cy = (sigmoidf_(ty) + gy) * 32.f;
  float bw = expf(tw) * ANCW[a] * 32.f;
  float bh = expf(th) * ANCH_[a] * 32.f;
  float x1 = fminf(fmaxf((cx - 0.5f*bw) / 608.f, 0.f), 1.f);
  float y1 = fminf(fmaxf((cy - 0.5f*bh) / 608.f, 0.f), 1.f);
  float x2 = fminf(fmaxf((cx + 0.5f*bw) / 608.f, 0.f), 1.f);
  float y2 = fminf(fmaxf((cy + 0.5f*bh) / 608.f, 0.f), 1.f);
  out[n*4+0]=x1; out[n*4+1]=y1; out[n*4+2]=x2; out[n*4+3]=y2;
  out[7220 + n]  = score;
  out[9025 + n]  = (float)bi;
  out[10830 + n] = 0.f;          // keep init
  cls_i[n] = bi;
}

// ---------------- per-class rank (score desc, idx asc) ----------------
__global__ __launch_bounds__(256) void rank_k(const float* __restrict__ scores,
    const int* __restrict__ cls_i, int* __restrict__ ord, int* __restrict__ cnt){
  __shared__ float s_sc[N_BOX];
  __shared__ short s_cl[N_BOX];
  int tid = threadIdx.x;
  for (int j = tid; j < N_BOX; j += 256){ s_sc[j] = scores[j]; s_cl[j] = (short)cls_i[j]; }
  __syncthreads();
  int i = blockIdx.x*256 + tid;
  if (i >= N_BOX) return;
  float si = s_sc[i]; int ci = s_cl[i];
  int r = 0;
  #pragma unroll 8
  for (int j = 0; j < N_BOX; ++j){
    float sj = s_sc[j];
    int hit = (s_cl[j] == (short)ci) & ((sj > si) | ((sj == si) & (j < i)));
    r += hit;
  }
  ord[ci*N_BOX + r] = i;
  atomicAdd(&cnt[ci], 1);
}

// ---------------- per-class NMS on compacted sorted list ----------------
__global__ __launch_bounds__(256) void nms2_k(const float* __restrict__ boxes,
    const int* __restrict__ ord, const int* __restrict__ cnt, float* __restrict__ keep){
  __shared__ float X1[N_BOX], Y1[N_BOX], X2[N_BOX], Y2[N_BOX], AR[N_BOX];
  __shared__ unsigned char SUP[N_BOX];
  __shared__ int IDX[N_BOX];
  int c = blockIdx.x, tid = threadIdx.x;
  int n = cnt[c];
  for (int t = tid; t < n; t += 256){
    int bi = ord[c*N_BOX + t];
    float x1 = boxes[bi*4+0], y1 = boxes[bi*4+1], x2 = boxes[bi*4+2], y2 = boxes[bi*4+3];
    X1[t]=x1; Y1[t]=y1; X2[t]=x2; Y2[t]=y2; AR[t]=(x2-x1)*(y2-y1);
    SUP[t]=0; IDX[t]=bi;
  }
  __syncthreads();
  for (int k = 0; k < n; ++k){
    if (!SUP[k]){
      if (tid == 0) keep[IDX[k]] = 1.f;
      float ax1=X1[k], ay1=Y1[k], ax2=X2[k], ay2=Y2[k], areaA=AR[k];
      for (int j = k+1+tid; j < n; j += 256){
        float iw = fmaxf(1e-10f, fminf(ax2,X2[j]) - fmaxf(ax1,X1[j]));
        float ih = fmaxf(1e-10f, fminf(ay2,Y2[j]) - fmaxf(ay1,Y1[j]));
        float inter = iw*ih;
        float iou = inter / (areaA + AR[j] - inter);
        if (iou > 0.5f) SUP[j] = 1;
      }
    }
    __syncthreads();
  }
}

static inline size_t align256(size_t x){ return (x + 255) & ~(size_t)255; }

extern "C" void kernel_launch(void* const* d_in, const int* in_sizes, int n_in,
                              void* d_out, int out_size, void* d_ws, size_t ws_size,
                              hipStream_t stream){
  const float* feat2 = (const float*)d_in[0];   // (512,38,38)
  const float* feat3 = (const float*)d_in[1];   // (1024,19,19)
  const float* w1a = (const float*)d_in[2];
  const float* b1a = (const float*)d_in[3];
  const float* w1b = (const float*)d_in[4];
  const float* b1b = (const float*)d_in[5];
  const float* wr  = (const float*)d_in[6];
  const float* br  = (const float*)d_in[7];
  const float* w2  = (const float*)d_in[8];
  const float* b2  = (const float*)d_in[9];
  const float* wp  = (const float*)d_in[10];
  const float* bp  = (const float*)d_in[11];
  float* out = (float*)d_out;
  char* ws = (char*)d_ws;

  size_t off = 0;
  float* part = (float*)(ws + off); off = align256(off + (size_t)16*1024*NPIX*4);
  f16* wh   = (f16*)(ws + off); off = align256(off + (size_t)1024*1280*9*2);
  f16* wl   = (f16*)(ws + off); off = align256(off + (size_t)1024*1280*9*2);
  f16* a1h  = (f16*)(ws + off); off = align256(off + (size_t)NPIX*1024*2);
  f16* a1l  = (f16*)(ws + off); off = align256(off + (size_t)NPIX*1024*2);
  f16* a2h  = (f16*)(ws + off); off = align256(off + (size_t)NPIX*1024*2);
  f16* a2l  = (f16*)(ws + off); off = align256(off + (size_t)NPIX*1024*2);
  f16* a3h  = (f16*)(ws + off); off = align256(off + (size_t)NPIX*1024*2);
  f16* a3l  = (f16*)(ws + off); off = align256(off + (size_t)NPIX*1024*2);
  f16* cath = (f16*)(ws + off); off = align256(off + (size_t)NPIX*1280*2);
  f16* catl = (f16*)(ws + off); off = align256(off + (size_t)NPIX*1280*2);
  float* pred = (float*)(ws + off); off = align256(off + (size_t)125*NPIX*4);
  float* wrT  = (float*)(ws + off); off = align256(off + (size_t)512*64*4);
  float* wpT  = (float*)(ws + off); off = align256(off + (size_t)1024*125*4);
  int* cls_i  = (int*)(ws + off); off = align256(off + (size_t)N_BOX*4);
  int* ord    = (int*)(ws + off); off = align256(off + (size_t)NCLS*N_BOX*4);
  int* cnt    = (int*)(ws + off); off = align256(off + (size_t)NCLS*4);

  transpose_k<<<(64*512 + 255)/256, 256, 0, stream>>>(wr, wrT, 64, 512);
  transpose_k<<<(125*1024 + 255)/256, 256, 0, stream>>>(wp, wpT, 125, 1024);
  act1prep_k<<<(NPIX*1024 + 255)/256, 256, 0, stream>>>(feat3, a1h, a1l);
  reorg_conv_k<<<361, 256, 0, stream>>>(feat2, wrT, br, cath, catl);

  // conv1: act1 (Cin=1024) -> act2
  wprep_k<<<(1024*1024 + 255)/256, 256, 0, stream>>>(w1a, wh, wl, 1024, 1024*1024);
  { dim3 g(8, 3, 16);
    conv_mfma_k<<<g, 256, 0, stream>>>(wh, wl, a1h, a1l, part, 1024, 18, 32); }
  reduce16v_k<<<(1024*NPIX + 255)/256, 256, 0, stream>>>(part, b1a, a2h, a2l, 1024, 0, 16);

  // conv2: act2 (Cin=1024) -> cat[256:1280)
  wprep_k<<<(1024*1024 + 255)/256, 256, 0, stream>>>(w1b, wh, wl, 1024, 1024*1024);
  { dim3 g(8, 3, 16);
    conv_mfma_k<<<g, 256, 0, stream>>>(wh, wl, a2h, a2l, part, 1024, 18, 32); }
  reduce16v_k<<<(1024*NPIX + 255)/256, 256, 0, stream>>>(part, b1b, cath, catl, 1280, 256, 16);

  // conv3: cat (Cin=1280) -> act3
  wprep_k<<<(1024*1280 + 255)/256, 256, 0, stream>>>(w2, wh, wl, 1280, 1024*1280);
  { dim3 g(8, 3, 15);
    conv_mfma_k<<<g, 256, 0, stream>>>(wh, wl, cath, catl, part, 1280, 24, 40); }
  reduce16v_k<<<(1024*NPIX + 255)/256, 256, 0, stream>>>(part, b2, a3h, a3l, 1024, 0, 15);

  // pred 1x1 + decode + NMS
  pred_conv_k<<<181, 256, 0, stream>>>(a3h, a3l, wpT, bp, pred);
  decode_k<<<8, 256, 0, stream>>>(pred, out, cls_i, cnt);
  rank_k<<<8, 256, 0, stream>>>(out + 7220, cls_i, ord, cnt);
  nms2_k<<<NCLS, 256, 0, stream>>>(out, ord, cnt, out + 10830);
}

// Round 5
// 320.347 us; speedup vs baseline: 4.7729x; 1.1666x over previous
//
#include <hip/hip_runtime.h>

typedef _Float16 f16;
typedef _Float16 f16x8 __attribute__((ext_vector_type(8)));
typedef float f32x4 __attribute__((ext_vector_type(4)));

#define N_BOX 1805
#define NPIX 361
#define NCLS 20

__device__ __forceinline__ float leakyf(float x){ return x > 0.f ? x : 0.1f*x; }
__device__ __forceinline__ float sigmoidf_(float x){ return 1.f/(1.f + expf(-x)); }

// ---------------- small transpose: dst[C][R] = src[R][C] (fp32, for wrT/wpT) ----------------
__global__ void transpose_k(const float* __restrict__ src, float* __restrict__ dst, int R, int C){
  int i = blockIdx.x*256 + threadIdx.x;
  if (i < R*C){ int r = i / C, c = i % C; dst[c*R + r] = src[i]; }
}

// ---------------- weight prep: w[Cout][Cin][9] fp32 -> whi/wlo[Cout][9][Cin] f16, scaled x64 ----------------
__global__ void wprep_k(const float* __restrict__ w, f16* __restrict__ whi, f16* __restrict__ wlo,
                        int Cin, int total){
  int i = blockIdx.x*256 + threadIdx.x;   // over Cout*Cin
  if (i >= total) return;
  int co = i / Cin, ci = i - co*Cin;
  const float* src = w + (size_t)i*9;     // [co][ci][0..9)
  int K9 = 9*Cin;
  size_t dbase = (size_t)co*K9 + ci;
  #pragma unroll
  for (int t = 0; t < 9; ++t){
    float v = src[t]*64.f;
    f16 hi = (f16)v;
    f16 lo = (f16)(v - (float)hi);
    whi[dbase + (size_t)t*Cin] = hi;
    wlo[dbase + (size_t)t*Cin] = lo;
  }
}

// ---------------- act1 prep: feat3[1024][361] fp32 -> a1hi/a1lo[361][1024] f16 ----------------
__global__ void act1prep_k(const float* __restrict__ feat3, f16* __restrict__ ah, f16* __restrict__ al){
  int i = blockIdx.x*256 + threadIdx.x;  // over 361*1024
  if (i >= NPIX*1024) return;
  int p = i >> 10, c = i & 1023;
  float v = feat3[c*NPIX + p];
  f16 hi = (f16)v; f16 lo = (f16)(v - (float)hi);
  ah[i] = hi; al[i] = lo;
}

// ---------------- reorg path: leaky(conv1x1(feat2, wr)+br) -> reorg -> cat[ ][0:256) f16 hi/lo ----------------
__global__ __launch_bounds__(256) void reorg_conv_k(const float* __restrict__ feat2,
    const float* __restrict__ wrT, const float* __restrict__ br,
    f16* __restrict__ cath, f16* __restrict__ catl){
  int c  = threadIdx.x & 63;
  int pq = threadIdx.x >> 6;
  int pix = blockIdx.x*4 + pq;      // 0..1443
  int y = pix / 38, x = pix % 38;
  __shared__ float s_in[64][4];
  float acc = br[c];
  for (int cb = 0; cb < 512; cb += 64){
    __syncthreads();
    { int k = threadIdx.x >> 2, pp = threadIdx.x & 3;
      s_in[k][pp] = feat2[(cb + k)*1444 + blockIdx.x*4 + pp]; }
    __syncthreads();
    #pragma unroll
    for (int k = 0; k < 64; ++k)
      acc = fmaf(wrT[(cb+k)*64 + c], s_in[k][pq], acc);
  }
  float v = leakyf(acc);
  int co = ((y & 1)*2 + (x & 1))*64 + c;   // reorg channel mapping
  int p = (y>>1)*19 + (x>>1);
  f16 hi = (f16)v; f16 lo = (f16)(v - (float)hi);
  size_t o = (size_t)p*1280 + co;
  cath[o] = hi; catl[o] = lo;
}

// ---------------- 3x3 conv as MFMA GEMM (f16 2-term split, 3 passes), split-K partials ----------------
__global__ __launch_bounds__(256) void conv_mfma_k(
    const f16* __restrict__ whi, const f16* __restrict__ wlo,
    const f16* __restrict__ ahi, const f16* __restrict__ alo,
    float* __restrict__ part, int Cin, int chunks, int cpt)
{
  const int K9 = 9*Cin;
  int cob = blockIdx.x * 128;
  int px0 = blockIdx.y * 128;
  int ks  = blockIdx.z;
  int kc0 = ks * chunks;
  int tid = threadIdx.x;

  __shared__ f16 sAh[128*32], sAl[128*32], sBh[128*32], sBl[128*32];

  int r = tid >> 1, h = tid & 1;
  int wb0 = ((r*64 + h*32)      ) ^ ((r&7)<<4);
  int wb1 = ((r*64 + h*32 + 16) ) ^ ((r&7)<<4);
  const f16* wArowh = whi + (size_t)(cob + r)*K9 + h*16;
  const f16* wArowl = wlo + (size_t)(cob + r)*K9 + h*16;
  int p = px0 + r;
  int py = p / 19, px = p - py*19;

  int lane = tid & 63, wid = tid >> 6;
  int lrow = lane & 15, lgrp = lane >> 4;
  int wr = wid >> 1, wc = wid & 1;
  int swz = (lrow & 7) << 4;
  int aoff[4], boff[4];
  #pragma unroll
  for (int m = 0; m < 4; ++m){
    int rA = wr*64 + m*16 + lrow;
    aoff[m] = (rA*64 + lgrp*16) ^ swz;
    int rB = wc*64 + m*16 + lrow;
    boff[m] = (rB*64 + lgrp*16) ^ swz;
  }

  f32x4 acc[4][4] = {};

  for (int kc = kc0; kc < kc0 + chunks; ++kc){
    int t = kc / cpt;                   // tap 0..8
    int ci0 = (kc - t*cpt) * 32;
    int dy = t / 3, dx = t - dy*3;
    int yy = py + dy - 1, xx = px + dx - 1;
    bool bvalid = (p < NPIX) && ((unsigned)yy < 19u) && ((unsigned)xx < 19u);

    f16x8 a0 = *(const f16x8*)(wArowh + (size_t)kc*32);
    f16x8 a1 = *(const f16x8*)(wArowh + (size_t)kc*32 + 8);
    f16x8 a2 = *(const f16x8*)(wArowl + (size_t)kc*32);
    f16x8 a3 = *(const f16x8*)(wArowl + (size_t)kc*32 + 8);
    f16x8 b0 = {}, b1 = {}, b2 = {}, b3 = {};
    if (bvalid){
      const f16* bh_src = ahi + (size_t)(yy*19+xx)*Cin + ci0 + h*16;
      const f16* bl_src = alo + (size_t)(yy*19+xx)*Cin + ci0 + h*16;
      b0 = *(const f16x8*)(bh_src);
      b1 = *(const f16x8*)(bh_src + 8);
      b2 = *(const f16x8*)(bl_src);
      b3 = *(const f16x8*)(bl_src + 8);
    }
    __syncthreads();
    *(f16x8*)((char*)sAh + wb0) = a0; *(f16x8*)((char*)sAh + wb1) = a1;
    *(f16x8*)((char*)sAl + wb0) = a2; *(f16x8*)((char*)sAl + wb1) = a3;
    *(f16x8*)((char*)sBh + wb0) = b0; *(f16x8*)((char*)sBh + wb1) = b1;
    *(f16x8*)((char*)sBl + wb0) = b2; *(f16x8*)((char*)sBl + wb1) = b3;
    __syncthreads();

    f16x8 bh[4], bl[4];
    #pragma unroll
    for (int n = 0; n < 4; ++n){
      bh[n] = *(const f16x8*)((char*)sBh + boff[n]);
      bl[n] = *(const f16x8*)((char*)sBl + boff[n]);
    }
    #pragma unroll
    for (int m = 0; m < 4; ++m){
      f16x8 ah = *(const f16x8*)((char*)sAh + aoff[m]);
      f16x8 al = *(const f16x8*)((char*)sAl + aoff[m]);
      #pragma unroll
      for (int n = 0; n < 4; ++n){
        acc[m][n] = __builtin_amdgcn_mfma_f32_16x16x32_f16(ah, bh[n], acc[m][n], 0,0,0);
        acc[m][n] = __builtin_amdgcn_mfma_f32_16x16x32_f16(ah, bl[n], acc[m][n], 0,0,0);
        acc[m][n] = __builtin_amdgcn_mfma_f32_16x16x32_f16(al, bh[n], acc[m][n], 0,0,0);
      }
    }
  }

  #pragma unroll
  for (int m = 0; m < 4; ++m){
    #pragma unroll
    for (int n = 0; n < 4; ++n){
      int pp = px0 + wc*64 + n*16 + lrow;
      if (pp < NPIX){
        int co = cob + wr*64 + m*16 + lgrp*4;
        size_t base = ((size_t)ks*1024 + co)*NPIX + pp;
        part[base          ] = acc[m][n][0];
        part[base +   NPIX ] = acc[m][n][1];
        part[base + 2*NPIX ] = acc[m][n][2];
        part[base + 3*NPIX ] = acc[m][n][3];
      }
    }
  }
}

// ---------------- reduce split-K partials (x1/64) + bias + leaky -> transposed f16 hi/lo ----------------
__global__ void reduce16v_k(const float* __restrict__ part, const float* __restrict__ bias,
                            f16* __restrict__ dhi, f16* __restrict__ dlo,
                            int Cstride, int Coff, int splitk){
  int i = blockIdx.x*256 + threadIdx.x;
  if (i >= 1024*NPIX) return;
  int co = i / NPIX, p = i - co*NPIX;
  float s = 0.f;
  for (int k = 0; k < splitk; ++k) s += part[(size_t)k*1024*NPIX + i];
  float v = leakyf(s*0.015625f + bias[co]);
  f16 hi = (f16)v;
  f16 lo = (f16)(v - (float)hi);
  size_t o = (size_t)p*Cstride + Coff + co;
  dhi[o] = hi; dlo[o] = lo;
}

// ---------------- pred 1x1 conv: act3[361][1024] (hi+lo) -> 125 ----------------
__global__ __launch_bounds__(256) void pred_conv_k(const f16* __restrict__ a3h, const f16* __restrict__ a3l,
    const float* __restrict__ wpT, const float* __restrict__ bp, float* __restrict__ pred){
  int c = threadIdx.x & 127, ph = threadIdx.x >> 7;
  int pix = blockIdx.x*2 + ph;
  __shared__ float s_in[64][2];
  float acc = 0.f;
  for (int cb = 0; cb < 1024; cb += 64){
    __syncthreads();
    if (threadIdx.x < 128){
      int k = threadIdx.x & 63, pp = threadIdx.x >> 6;
      int px2 = blockIdx.x*2 + pp;
      float v = 0.f;
      if (px2 < NPIX){
        size_t o = (size_t)px2*1024 + cb + k;
        v = (float)a3h[o] + (float)a3l[o];
      }
      s_in[k][pp] = v;
    }
    __syncthreads();
    if (c < 125){
      #pragma unroll
      for (int k = 0; k < 64; ++k)
        acc = fmaf(wpT[(cb+k)*125 + c], s_in[k][ph], acc);
    }
  }
  if (c < 125 && pix < NPIX) pred[c*NPIX + pix] = acc + bp[c];
}

// ---------------- decode boxes / scores / argmax (+ zero class counters) ----------------
__device__ const float ANCW[5] = {1.19f, 2.79f, 4.53f, 8.06f, 10.32f};
__device__ const float ANCH_[5] = {1.98f, 4.59f, 8.92f, 5.29f, 10.65f};

__global__ void decode_k(const float* __restrict__ pred, float* __restrict__ out,
                         int* __restrict__ cls_i, int* __restrict__ cnt){
  int n = blockIdx.x*256 + threadIdx.x;
  if (blockIdx.x == 0 && threadIdx.x < NCLS) cnt[threadIdx.x] = 0;
  if (n >= N_BOX) return;
  int p = n / 5, a = n % 5;
  float conf = pred[a*NPIX + p];
  float cl[20]; float m = -1e30f;
  #pragma unroll
  for (int k = 0; k < 20; ++k){ cl[k] = pred[(5 + a*20 + k)*NPIX + p]; m = fmaxf(m, cl[k]); }
  float s = 0.f;
  #pragma unroll
  for (int k = 0; k < 20; ++k){ cl[k] = expf(cl[k]-m); s += cl[k]; }
  int bi = 0; float bv = cl[0];
  #pragma unroll
  for (int k = 1; k < 20; ++k) if (cl[k] > bv){ bv = cl[k]; bi = k; }
  float score = sigmoidf_(conf) * (bv / s);
  float tx = pred[(105 + a*4 + 0)*NPIX + p];
  float ty = pred[(105 + a*4 + 1)*NPIX + p];
  float tw = pred[(105 + a*4 + 2)*NPIX + p];
  float th = pred[(105 + a*4 + 3)*NPIX + p];
  float gx = (float)(p % 19), gy = (float)(p / 19);
  float cx = (sigmoidf_(tx) + gx) * 32.f;
  float cy = (sigmoidf_(ty) + gy) * 32.f;
  float bw = expf(tw) * ANCW[a] * 32.f;
  float bh = expf(th) * ANCH_[a] * 32.f;
  float x1 = fminf(fmaxf((cx - 0.5f*bw) / 608.f, 0.f), 1.f);
  float y1 = fminf(fmaxf((cy - 0.5f*bh) / 608.f, 0.f), 1.f);
  float x2 = fminf(fmaxf((cx + 0.5f*bw) / 608.f, 0.f), 1.f);
  float y2 = fminf(fmaxf((cy + 0.5f*bh) / 608.f, 0.f), 1.f);
  out[n*4+0]=x1; out[n*4+1]=y1; out[n*4+2]=x2; out[n*4+3]=y2;
  out[7220 + n]  = score;
  out[9025 + n]  = (float)bi;
  out[10830 + n] = 0.f;          // keep init
  cls_i[n] = bi;
}

// ---------------- per-class rank, wave-parallel (1 wave per box) ----------------
__global__ __launch_bounds__(256) void rank_k(const float* __restrict__ scores,
    const int* __restrict__ cls_i, int* __restrict__ ord, int* __restrict__ cnt){
  __shared__ float s_sc[N_BOX];
  __shared__ short s_cl[N_BOX];
  int tid = threadIdx.x;
  for (int j = tid; j < N_BOX; j += 256){ s_sc[j] = scores[j]; s_cl[j] = (short)cls_i[j]; }
  __syncthreads();
  int wid = tid >> 6, lane = tid & 63;
  int i = blockIdx.x*4 + wid;
  if (i >= N_BOX) return;
  float si = s_sc[i]; short ci = s_cl[i];
  int r = 0;
  for (int j = lane; j < N_BOX; j += 64){
    float sj = s_sc[j];
    r += (int)((s_cl[j] == ci) & ((sj > si) | ((sj == si) & (j < i))));
  }
  #pragma unroll
  for (int o = 32; o; o >>= 1) r += __shfl_down(r, o);
  if (lane == 0){
    ord[ci*N_BOX + r] = i;
    atomicAdd(&cnt[ci], 1);
  }
}

// ---------------- per-class NMS on compacted sorted list ----------------
__global__ __launch_bounds__(256) void nms2_k(const float* __restrict__ boxes,
    const int* __restrict__ ord, const int* __restrict__ cnt, float* __restrict__ keep){
  __shared__ float X1[N_BOX], Y1[N_BOX], X2[N_BOX], Y2[N_BOX], AR[N_BOX];
  __shared__ unsigned char SUP[N_BOX];
  __shared__ int IDX[N_BOX];
  int c = blockIdx.x, tid = threadIdx.x;
  int n = cnt[c];
  for (int t = tid; t < n; t += 256){
    int bi = ord[c*N_BOX + t];
    float x1 = boxes[bi*4+0], y1 = boxes[bi*4+1], x2 = boxes[bi*4+2], y2 = boxes[bi*4+3];
    X1[t]=x1; Y1[t]=y1; X2[t]=x2; Y2[t]=y2; AR[t]=(x2-x1)*(y2-y1);
    SUP[t]=0; IDX[t]=bi;
  }
  __syncthreads();
  for (int k = 0; k < n; ++k){
    if (!SUP[k]){
      if (tid == 0) keep[IDX[k]] = 1.f;
      float ax1=X1[k], ay1=Y1[k], ax2=X2[k], ay2=Y2[k], areaA=AR[k];
      for (int j = k+1+tid; j < n; j += 256){
        float iw = fmaxf(1e-10f, fminf(ax2,X2[j]) - fmaxf(ax1,X1[j]));
        float ih = fmaxf(1e-10f, fminf(ay2,Y2[j]) - fmaxf(ay1,Y1[j]));
        float inter = iw*ih;
        float iou = inter / (areaA + AR[j] - inter);
        if (iou > 0.5f) SUP[j] = 1;
      }
    }
    __syncthreads();
  }
}

static inline size_t align256(size_t x){ return (x + 255) & ~(size_t)255; }

extern "C" void kernel_launch(void* const* d_in, const int* in_sizes, int n_in,
                              void* d_out, int out_size, void* d_ws, size_t ws_size,
                              hipStream_t stream){
  const float* feat2 = (const float*)d_in[0];   // (512,38,38)
  const float* feat3 = (const float*)d_in[1];   // (1024,19,19)
  const float* w1a = (const float*)d_in[2];
  const float* b1a = (const float*)d_in[3];
  const float* w1b = (const float*)d_in[4];
  const float* b1b = (const float*)d_in[5];
  const float* wr  = (const float*)d_in[6];
  const float* br  = (const float*)d_in[7];
  const float* w2  = (const float*)d_in[8];
  const float* b2  = (const float*)d_in[9];
  const float* wp  = (const float*)d_in[10];
  const float* bp  = (const float*)d_in[11];
  float* out = (float*)d_out;
  char* ws = (char*)d_ws;

  size_t off = 0;
  float* part = (float*)(ws + off); off = align256(off + (size_t)16*1024*NPIX*4);
  f16* wh   = (f16*)(ws + off); off = align256(off + (size_t)1024*1280*9*2);
  f16* wl   = (f16*)(ws + off); off = align256(off + (size_t)1024*1280*9*2);
  f16* a1h  = (f16*)(ws + off); off = align256(off + (size_t)NPIX*1024*2);
  f16* a1l  = (f16*)(ws + off); off = align256(off + (size_t)NPIX*1024*2);
  f16* a2h  = (f16*)(ws + off); off = align256(off + (size_t)NPIX*1024*2);
  f16* a2l  = (f16*)(ws + off); off = align256(off + (size_t)NPIX*1024*2);
  f16* a3h  = (f16*)(ws + off); off = align256(off + (size_t)NPIX*1024*2);
  f16* a3l  = (f16*)(ws + off); off = align256(off + (size_t)NPIX*1024*2);
  f16* cath = (f16*)(ws + off); off = align256(off + (size_t)NPIX*1280*2);
  f16* catl = (f16*)(ws + off); off = align256(off + (size_t)NPIX*1280*2);
  float* pred = (float*)(ws + off); off = align256(off + (size_t)125*NPIX*4);
  float* wrT  = (float*)(ws + off); off = align256(off + (size_t)512*64*4);
  float* wpT  = (float*)(ws + off); off = align256(off + (size_t)1024*125*4);
  int* cls_i  = (int*)(ws + off); off = align256(off + (size_t)N_BOX*4);
  int* ord    = (int*)(ws + off); off = align256(off + (size_t)NCLS*N_BOX*4);
  int* cnt    = (int*)(ws + off); off = align256(off + (size_t)NCLS*4);

  transpose_k<<<(64*512 + 255)/256, 256, 0, stream>>>(wr, wrT, 64, 512);
  transpose_k<<<(125*1024 + 255)/256, 256, 0, stream>>>(wp, wpT, 125, 1024);
  act1prep_k<<<(NPIX*1024 + 255)/256, 256, 0, stream>>>(feat3, a1h, a1l);
  reorg_conv_k<<<361, 256, 0, stream>>>(feat2, wrT, br, cath, catl);

  // conv1: act1 (Cin=1024) -> act2
  wprep_k<<<(1024*1024 + 255)/256, 256, 0, stream>>>(w1a, wh, wl, 1024, 1024*1024);
  { dim3 g(8, 3, 16);
    conv_mfma_k<<<g, 256, 0, stream>>>(wh, wl, a1h, a1l, part, 1024, 18, 32); }
  reduce16v_k<<<(1024*NPIX + 255)/256, 256, 0, stream>>>(part, b1a, a2h, a2l, 1024, 0, 16);

  // conv2: act2 (Cin=1024) -> cat[256:1280)
  wprep_k<<<(1024*1024 + 255)/256, 256, 0, stream>>>(w1b, wh, wl, 1024, 1024*1024);
  { dim3 g(8, 3, 16);
    conv_mfma_k<<<g, 256, 0, stream>>>(wh, wl, a2h, a2l, part, 1024, 18, 32); }
  reduce16v_k<<<(1024*NPIX + 255)/256, 256, 0, stream>>>(part, b1b, cath, catl, 1280, 256, 16);

  // conv3: cat (Cin=1280) -> act3
  wprep_k<<<(1024*1280 + 255)/256, 256, 0, stream>>>(w2, wh, wl, 1280, 1024*1280);
  { dim3 g(8, 3, 15);
    conv_mfma_k<<<g, 256, 0, stream>>>(wh, wl, cath, catl, part, 1280, 24, 40); }
  reduce16v_k<<<(1024*NPIX + 255)/256, 256, 0, stream>>>(part, b2, a3h, a3l, 1024, 0, 15);

  // pred 1x1 + decode + NMS
  pred_conv_k<<<181, 256, 0, stream>>>(a3h, a3l, wpT, bp, pred);
  decode_k<<<8, 256, 0, stream>>>(pred, out, cls_i, cnt);
  rank_k<<<(N_BOX + 3)/4, 256, 0, stream>>>(out + 7220, cls_i, ord, cnt);
  nms2_k<<<NCLS, 256, 0, stream>>>(out, ord, cnt, out + 10830);
}